// Round 24
// baseline (460.188 us; speedup 1.0000x reference)
//
#include <hip/hip_runtime.h>
#include <math.h>

#define BB 4
#define LL 1024
#define DIN 64
#define DD 512
#define HH 8
#define DH 64
#define NLAYER 3
#define DFF 2048
#define FEAT 530
#define FEATP 576
#define MM 4096

typedef float f32x4 __attribute__((ext_vector_type(4)));
typedef short s16x8 __attribute__((ext_vector_type(8)));

__device__ __forceinline__ unsigned short f2bf(float f) {
    unsigned int u = __float_as_uint(f);
    u += 0x7fffu + ((u >> 16) & 1u);
    return (unsigned short)(u >> 16);
}
__device__ __forceinline__ float bf2f(unsigned short u) {
    return __uint_as_float(((unsigned int)u) << 16);
}
__device__ __forceinline__ float gelu_exact(float x) {
    return 0.5f * x * (1.0f + erff(x * 0.7071067811865475f));
}
__device__ __forceinline__ float wave_reduce_sum(float v) {
    #pragma unroll
    for (int o = 32; o; o >>= 1) v += __shfl_down(v, o);
    return v;
}
__device__ __forceinline__ void gload16(const unsigned short* g, unsigned short* l) {
    __builtin_amdgcn_global_load_lds(
        (const __attribute__((address_space(1))) unsigned int*)g,
        (__attribute__((address_space(3))) unsigned int*)l, 16, 0, 0);
}
__device__ __forceinline__ void cvt16(const float* src, unsigned short* dst) {
    float4 f0 = ((const float4*)src)[0];
    float4 f1 = ((const float4*)src)[1];
    float4 f2 = ((const float4*)src)[2];
    float4 f3 = ((const float4*)src)[3];
    ushort4 o0, o1, o2, o3;
    o0.x = f2bf(f0.x); o0.y = f2bf(f0.y); o0.z = f2bf(f0.z); o0.w = f2bf(f0.w);
    o1.x = f2bf(f1.x); o1.y = f2bf(f1.y); o1.z = f2bf(f1.z); o1.w = f2bf(f1.w);
    o2.x = f2bf(f2.x); o2.y = f2bf(f2.y); o2.z = f2bf(f2.z); o2.w = f2bf(f2.w);
    o3.x = f2bf(f3.x); o3.y = f2bf(f3.y); o3.z = f2bf(f3.z); o3.w = f2bf(f3.w);
    ((ushort4*)dst)[0] = o0;
    ((ushort4*)dst)[1] = o1;
    ((ushort4*)dst)[2] = o2;
    ((ushort4*)dst)[3] = o3;
}
// fold gamma into 16 weights; accumulate c1 (= sum g*W) and c2 (= sum b*W)
__device__ __forceinline__ void cvt16_fold(const float* src, const float* g, const float* bt,
                                           unsigned short* dst, float& pc1, float& pc2) {
    #pragma unroll
    for (int q = 0; q < 4; ++q) {
        float4 w4 = ((const float4*)src)[q];
        float4 g4 = ((const float4*)g)[q];
        float4 b4 = ((const float4*)bt)[q];
        float fw0 = w4.x * g4.x, fw1 = w4.y * g4.y, fw2 = w4.z * g4.z, fw3 = w4.w * g4.w;
        ushort4 o;
        o.x = f2bf(fw0); o.y = f2bf(fw1); o.z = f2bf(fw2); o.w = f2bf(fw3);
        ((ushort4*)dst)[q] = o;
        pc1 += (fw0 + fw1) + (fw2 + fw3);
        pc2 += (b4.x * w4.x + b4.y * w4.y) + (b4.z * w4.z + b4.w * w4.w);
    }
}

// ------------- small prologue: PE/z (1024) | small converts + stat-zero (256) | delay matvec (64) -------------
#define NSTAT_FLOATS (7 * MM * 2 + 2 * 3 * 1536 + 2 * 3 * 2048)
__global__ __launch_bounds__(256) void prologue_kernel(
    const float* __restrict__ c_local, const float* __restrict__ c_sink,
    const int* __restrict__ lengths,
    const float* __restrict__ beta_p, const float* __restrict__ floor_p,
    const float* __restrict__ gamma_p,
    unsigned short* __restrict__ Z, float* __restrict__ srow,
    const float* __restrict__ x, const float* __restrict__ in_w,
    const float* __restrict__ cpe_w,
    unsigned short* __restrict__ x_bf, unsigned short* __restrict__ w_in,
    unsigned short* __restrict__ w_cpe,
    const float* __restrict__ delay, const float* __restrict__ de_w1, const float* __restrict__ de_b1,
    const float* __restrict__ de_w2, const float* __restrict__ de_b2,
    float* __restrict__ e_pre, float* __restrict__ zbuf)
{
    int blk = blockIdx.x;
    int t = threadIdx.x;

    if (blk < LL) {
        int l = blk;
        for (int d = t; d < DD; d += 256) {
            int i = d >> 1;
            float dv = expf((float)(2 * i) * (-0.017988946135618352f)); // -ln(1e4)/512
            float ang = (float)l * dv;
            unsigned short pv = f2bf((d & 1) ? cosf(ang) : sinf(ang));
            #pragma unroll
            for (int bb = 0; bb < 4; ++bb)
                Z[(size_t)(bb * LL + l) * FEATP + d] = pv;
        }
        {
            int bb = t >> 6, j = t & 63;
            float cl = c_local[(size_t)bb * LL + l]; cl = fminf(fmaxf(cl, 0.f), 1.f);
            float cs = c_sink [(size_t)bb * LL + l]; cs = fminf(fmaxf(cs, 0.f), 1.f);
            float v = 0.f;
            if (j == 0) v = cl;
            else if (j == 1) v = cs;
            else if (j < 10)  { float c = (float)(j - 2) * (1.0f / 7.0f);  float df = (cl - c) / 0.200001f; v = expf(-0.5f * df * df); }
            else if (j < 18)  { float c = (float)(j - 10) * (1.0f / 7.0f); float df = (cs - c) / 0.200001f; v = expf(-0.5f * df * df); }
            Z[(size_t)(bb * LL + l) * FEATP + 512 + j] = (j < 18) ? f2bf(v) : 0;
            if (j == 32) {
                float sv = (*beta_p) * ((*floor_p) + (1.f - (*floor_p)) * powf(cs + 1e-6f, *gamma_p));
                srow[bb * LL + l] = (l < lengths[bb]) ? sv : 0.f;
            }
        }
    } else if (blk < LL + 256) {
        const int N0s = MM * DIN;
        const int N1s = N0s + 512 * 64;
        const int NCHs = N1s / 16;
        int vb = blk - LL;
        for (int c = vb * 256 + t; c < NCHs; c += 256 * 256) {
            int i = c * 16;
            if (i < N0s) cvt16(x + i, x_bf + i);
            else         cvt16(in_w + (i - N0s), w_in + (i - N0s));
        }
        for (int j = vb * 256 + t; j < 512 * FEATP; j += 256 * 256) {
            int r = j / FEATP, c2 = j - r * FEATP;
            w_cpe[j] = (c2 < FEAT) ? f2bf(cpe_w[(size_t)r * FEAT + c2]) : 0;
        }
        // zero stats/c1/c2 region (consumed via atomics later in the graph)
        for (int j = vb * 256 + t; j < NSTAT_FLOATS; j += 256 * 256)
            zbuf[j] = 0.f;
    } else {
        __shared__ float g1[DD];
        int idx = blk - (LL + 256);
        int b  = idx >> 4;
        int r0 = (idx & 15) * 32;
        float d0 = delay[b];
        g1[t]       = gelu_exact(d0 * de_w1[t]       + de_b1[t]);
        g1[t + 256] = gelu_exact(d0 * de_w1[t + 256] + de_b1[t + 256]);
        __syncthreads();
        int r = t >> 3, c = t & 7;
        const float* wr = de_w2 + (size_t)(r0 + r) * DD + c * 64;
        const float* gc = g1 + c * 64;
        float s = 0.f;
        #pragma unroll
        for (int j = 0; j < 64; j += 4) {
            float4 a4 = *(const float4*)(wr + j);
            s += a4.x * gc[j] + a4.y * gc[j+1] + a4.z * gc[j+2] + a4.w * gc[j+3];
        }
        s += __shfl_xor(s, 1);
        s += __shfl_xor(s, 2);
        s += __shfl_xor(s, 4);
        if (c == 0) e_pre[(size_t)b * DD + r0 + r] = s + de_b2[r0 + r];
    }
}

// ---- GEMM body (BK=64, dbuf LDS, runtime mode) ----
// MODE 0: f32 out ; 1: bf16 out ; 2: bf16 out = acc+bias+bf16 resid (+stats accum) ;
// 4: bf16 out, bias by ROW ;
// 5: bf16 out = LN-folded row epilogue ; 6: LN-folded col epilogue (V^T) ;
// 7: mode 5 + gelu
template<int BM, int BN, int FM, int FN, int WGN>
__device__ __forceinline__ void gemm_body(
    const unsigned short* __restrict__ A, const unsigned short* __restrict__ W,
    const float* __restrict__ bias, const unsigned short* __restrict__ residb,
    float* __restrict__ outf, unsigned short* __restrict__ outb,
    int M, int N, int K, int mode, int bm, int bn,
    unsigned short* As, unsigned short* Ws,
    const float* __restrict__ c1, const float* __restrict__ c2,
    const float* __restrict__ statsIn, float* __restrict__ statsOut)
{
    int t = threadIdx.x;
    int lane = t & 63, wid = t >> 6;
    int wr = wid / WGN, wc = wid % WGN;
    int l15 = lane & 15, lg = lane >> 4;
    int sr = lane >> 3;
    int sc = ((lane & 7) ^ sr) * 8;
    int ph0 = (lg ^ (l15 & 7)) * 8;
    int ph1 = ((lg + 4) ^ (l15 & 7)) * 8;

    f32x4 acc[FM][FN] = {};
    int nk = K >> 6;

    auto stage = [&](int buf, int ks) {
        int kb = ks * 64;
        #pragma unroll
        for (int i = 0; i < BM / 32; ++i) {
            int row = wid * (BM / 4) + i * 8 + sr;
            gload16(A + (size_t)(bm + row) * K + kb + sc, &As[(size_t)buf * BM * 64 + (wid * (BM / 4) + i * 8) * 64]);
        }
        #pragma unroll
        for (int i = 0; i < BN / 32; ++i) {
            int row = wid * (BN / 4) + i * 8 + sr;
            gload16(W + (size_t)(bn + row) * K + kb + sc, &Ws[(size_t)buf * BN * 64 + (wid * (BN / 4) + i * 8) * 64]);
        }
    };

    stage(0, 0);
    __syncthreads();

    int cur = 0;
    for (int ks = 0; ks < nk; ++ks) {
        if (ks + 1 < nk) stage(cur ^ 1, ks + 1);
        s16x8 af0[FM], af1[FM], wf0[FN], wf1[FN];
        #pragma unroll
        for (int mi = 0; mi < FM; ++mi) {
            int row = wr * FM * 16 + mi * 16 + l15;
            af0[mi] = *(const s16x8*)&As[(size_t)cur * BM * 64 + row * 64 + ph0];
            af1[mi] = *(const s16x8*)&As[(size_t)cur * BM * 64 + row * 64 + ph1];
        }
        #pragma unroll
        for (int ni = 0; ni < FN; ++ni) {
            int row = wc * FN * 16 + ni * 16 + l15;
            wf0[ni] = *(const s16x8*)&Ws[(size_t)cur * BN * 64 + row * 64 + ph0];
            wf1[ni] = *(const s16x8*)&Ws[(size_t)cur * BN * 64 + row * 64 + ph1];
        }
        #pragma unroll
        for (int mi = 0; mi < FM; ++mi)
            #pragma unroll
            for (int ni = 0; ni < FN; ++ni) {
                acc[mi][ni] = __builtin_amdgcn_mfma_f32_16x16x32_bf16(af0[mi], wf0[ni], acc[mi][ni], 0, 0, 0);
                acc[mi][ni] = __builtin_amdgcn_mfma_f32_16x16x32_bf16(af1[mi], wf1[ni], acc[mi][ni], 0, 0, 0);
            }
        __syncthreads();
        cur ^= 1;
    }

    int rbase = (lane >> 4) * 4;
    if (mode == 5 || mode == 7) {
        // out = rstd[m]*acc - rstd[m]*mean[m]*c1[n] + c2[n] + bias[n]
        #pragma unroll
        for (int mi = 0; mi < FM; ++mi) {
            #pragma unroll
            for (int r2 = 0; r2 < 4; ++r2) {
                int m = bm + wr * FM * 16 + mi * 16 + rbase + r2;
                float sm = statsIn[2 * m], sq = statsIn[2 * m + 1];
                float mean = sm * (1.0f / DD);
                float rstd = rsqrtf(sq * (1.0f / DD) - mean * mean + 1e-5f);
                float rm = rstd * mean;
                #pragma unroll
                for (int ni = 0; ni < FN; ++ni) {
                    int n = bn + wc * FN * 16 + ni * 16 + l15;
                    float v = rstd * acc[mi][ni][r2] - rm * c1[n] + c2[n] + bias[n];
                    if (mode == 7) v = gelu_exact(v);
                    outb[(size_t)m * N + n] = f2bf(v);
                }
            }
        }
    } else if (mode == 6) {
        // V^T: stats indexed by output COLUMN (token); c1/c2/bias by output row (d)
        #pragma unroll
        for (int ni = 0; ni < FN; ++ni) {
            int n = bn + wc * FN * 16 + ni * 16 + l15;
            float sm = statsIn[2 * n], sq = statsIn[2 * n + 1];
            float mean = sm * (1.0f / DD);
            float rstd = rsqrtf(sq * (1.0f / DD) - mean * mean + 1e-5f);
            float rm = rstd * mean;
            #pragma unroll
            for (int mi = 0; mi < FM; ++mi) {
                #pragma unroll
                for (int r2 = 0; r2 < 4; ++r2) {
                    int m = bm + wr * FM * 16 + mi * 16 + rbase + r2;
                    float v = rstd * acc[mi][ni][r2] - rm * c1[m] + c2[m] + bias[m];
                    outb[(size_t)m * N + n] = f2bf(v);
                }
            }
        }
    } else {
        float rsum[FM][4], rsq[FM][4];
        #pragma unroll
        for (int mi = 0; mi < FM; ++mi)
            #pragma unroll
            for (int r2 = 0; r2 < 4; ++r2) { rsum[mi][r2] = 0.f; rsq[mi][r2] = 0.f; }
        #pragma unroll
        for (int mi = 0; mi < FM; ++mi) {
            #pragma unroll
            for (int ni = 0; ni < FN; ++ni) {
                int n = bn + wc * FN * 16 + ni * 16 + l15;
                float bzc = (mode == 4) ? 0.f : bias[n];
                #pragma unroll
                for (int r2 = 0; r2 < 4; ++r2) {
                    int m = bm + wr * FM * 16 + mi * 16 + rbase + r2;
                    float v = acc[mi][ni][r2] + ((mode == 4) ? bias[m] : bzc);
                    size_t o = (size_t)m * N + n;
                    if (mode == 0)      outf[o] = v;
                    else if (mode == 1) outb[o] = f2bf(v);
                    else if (mode == 2) {
                        v += bf2f(residb[o]);
                        outb[o] = f2bf(v);
                        rsum[mi][r2] += v; rsq[mi][r2] += v * v;
                    }
                    else                outb[o] = f2bf(v);
                }
            }
        }
        if (mode == 2 && statsOut) {
            #pragma unroll
            for (int mi = 0; mi < FM; ++mi) {
                #pragma unroll
                for (int r2 = 0; r2 < 4; ++r2) {
                    float a = rsum[mi][r2], q = rsq[mi][r2];
                    a += __shfl_xor(a, 1); q += __shfl_xor(q, 1);
                    a += __shfl_xor(a, 2); q += __shfl_xor(q, 2);
                    a += __shfl_xor(a, 4); q += __shfl_xor(q, 4);
                    a += __shfl_xor(a, 8); q += __shfl_xor(q, 8);
                    if (l15 == 0) {
                        int m = bm + wr * FM * 16 + mi * 16 + rbase + r2;
                        atomicAdd(&statsOut[2 * m], a);
                        atomicAdd(&statsOut[2 * m + 1], q);
                    }
                }
            }
        }
    }
}

// ---- standalone templated GEMM ----
template<int BM, int BN, int FM, int FN, int WGN, int MODE>
__global__ __launch_bounds__(256) void gemm_t(
    const unsigned short* __restrict__ A, const unsigned short* __restrict__ W,
    const float* __restrict__ bias, const unsigned short* __restrict__ residb,
    float* __restrict__ outf, unsigned short* __restrict__ outb,
    int M, int N, int K,
    const float* __restrict__ c1, const float* __restrict__ c2,
    const float* __restrict__ statsIn, float* __restrict__ statsOut)
{
    __shared__ __align__(16) unsigned short As[2 * BM * 64];
    __shared__ __align__(16) unsigned short Ws[2 * BN * 64];
    gemm_body<BM, BN, FM, FN, WGN>(A, W, bias, residb, outf, outb, M, N, K, MODE,
                                   blockIdx.y * BM, blockIdx.x * BN, As, Ws,
                                   c1, c2, statsIn, statsOut);
}

// ---- dual dispatch: h0 GEMM (512, bf16) + cpe GEMM (512) + folded big-weight converts (1024) ----
__global__ __launch_bounds__(256) void gemm_pre_dual(
    const unsigned short* __restrict__ x_bf, const unsigned short* __restrict__ w_in,
    const float* __restrict__ in_b, unsigned short* __restrict__ h,
    const unsigned short* __restrict__ Zb, const unsigned short* __restrict__ w_cpe,
    const float* __restrict__ cpe_b, float* __restrict__ cpe_pre,
    const float* __restrict__ inproj_w, const float* __restrict__ outproj_w,
    const float* __restrict__ ff_w1, const float* __restrict__ ff_w2,
    unsigned short* __restrict__ w_inproj, unsigned short* __restrict__ w_outproj,
    unsigned short* __restrict__ w_ff1, unsigned short* __restrict__ w_ff2,
    const float* __restrict__ ln1_g, const float* __restrict__ ln1_b,
    const float* __restrict__ ln2_g, const float* __restrict__ ln2_b,
    float* __restrict__ c1_in, float* __restrict__ c2_in,
    float* __restrict__ c1_ff, float* __restrict__ c2_ff)
{
    __shared__ __align__(16) unsigned short As[2 * 64 * 64];
    __shared__ __align__(16) unsigned short Ws[2 * 64 * 64];
    int id = blockIdx.x;
    if (id < 512) {
        gemm_body<64, 64, 2, 2, 2>(x_bf, w_in, in_b, nullptr, nullptr, h,
                                   MM, DD, DIN, 1, (id >> 3) * 64, (id & 7) * 64, As, Ws,
                                   nullptr, nullptr, nullptr, nullptr);
    } else if (id < 1024) {
        id -= 512;
        gemm_body<64, 64, 2, 2, 2>(Zb, w_cpe, cpe_b, nullptr, cpe_pre, nullptr,
                                   MM, DD, FEATP, 0, (id >> 3) * 64, (id & 7) * 64, As, Ws,
                                   nullptr, nullptr, nullptr, nullptr);
    } else {
        const int B0 = 3 * 1536 * 512;
        const int B1 = B0 + 3 * 512 * 512;
        const int B2 = B1 + 3 * 2048 * 512;
        const int B3 = B2 + 3 * 512 * 2048;
        const int NCH = B3 / 16;
        int vb = id - 1024;
        int t = threadIdx.x;
        for (int c = vb * 256 + t; c < NCH; c += 1024 * 256) {
            int i = c * 16;
            if (i < B0) {
                int L = i / (1536 * 512), rem = i - L * (1536 * 512);
                int n = rem >> 9, k = rem & 511;
                float pc1 = 0.f, pc2 = 0.f;
                cvt16_fold(inproj_w + i, ln1_g + L * 512 + k, ln1_b + L * 512 + k,
                           w_inproj + i, pc1, pc2);
                atomicAdd(&c1_in[L * 1536 + n], pc1);
                atomicAdd(&c2_in[L * 1536 + n], pc2);
            } else if (i < B1) {
                cvt16(outproj_w + (i - B0), w_outproj + (i - B0));
            } else if (i < B2) {
                int j = i - B1;
                int L = j / (2048 * 512), rem = j - L * (2048 * 512);
                int n = rem >> 9, k = rem & 511;
                float pc1 = 0.f, pc2 = 0.f;
                cvt16_fold(ff_w1 + j, ln2_g + L * 512 + k, ln2_b + L * 512 + k,
                           w_ff1 + j, pc1, pc2);
                atomicAdd(&c1_ff[L * 2048 + n], pc1);
                atomicAdd(&c2_ff[L * 2048 + n], pc2);
            } else {
                cvt16(ff_w2 + (i - B2), w_ff2 + (i - B2));
            }
        }
    }
}

// ---- dual dispatch: QK GEMM (1024 blocks, mode 5) + V^T GEMM (512 blocks, mode 6) ----
__global__ __launch_bounds__(256) void gemm_qkv_dual(
    const unsigned short* __restrict__ h,
    const unsigned short* __restrict__ wqk, const float* __restrict__ qk_bias,
    unsigned short* __restrict__ qkb,
    const unsigned short* __restrict__ wv, const float* __restrict__ v_bias,
    unsigned short* __restrict__ vtb,
    const float* __restrict__ c1q, const float* __restrict__ c2q,
    const float* __restrict__ c1v, const float* __restrict__ c2v,
    const float* __restrict__ stats)
{
    __shared__ __align__(16) unsigned short As[2 * 64 * 64];
    __shared__ __align__(16) unsigned short Ws[2 * 64 * 64];
    int id = blockIdx.x;
    if (id < 1024) {
        gemm_body<64, 64, 2, 2, 2>(h, wqk, qk_bias, nullptr, nullptr, qkb,
                                   MM, 1024, DD, 5, (id >> 4) * 64, (id & 15) * 64, As, Ws,
                                   c1q, c2q, stats, nullptr);
    } else {
        id -= 1024;
        gemm_body<64, 64, 2, 2, 2>(wv, h, v_bias, nullptr, nullptr, vtb,
                                   DD, MM, DD, 6, (id >> 6) * 64, (id & 63) * 64, As, Ws,
                                   c1v, c2v, stats, nullptr);
    }
}

// ------------- MFMA flash attention (unchanged) -------------
#define SK 72
#define SPB 72
__global__ __launch_bounds__(256) void attn_mfma(
    const unsigned short* __restrict__ qk, const unsigned short* __restrict__ Vt,
    const float* __restrict__ c_local, const float* __restrict__ srow,
    const int* __restrict__ lengths,
    const float* __restrict__ alpha_p,
    unsigned short* __restrict__ o)
{
    __shared__ __align__(16) unsigned short Ks[2][64 * SK];
    __shared__ __align__(16) unsigned short Vts[2][64 * SK];
    __shared__ __align__(16) unsigned short Psb[64 * SPB];

    int id = blockIdx.x;
    int q0 = (id & 15) * 64;
    int hh = (id >> 4) & 7;
    int b  = id >> 7;

    int t  = threadIdx.x;
    int lane = t & 63, w = t >> 6;
    int l15 = lane & 15, lg = lane >> 4;
    int len = lengths[b];
    int nt = (len + 63) >> 6;
    int kt0 = q0 >> 6;
    bool sink_blk = (q0 == 0);
    const float alpha = *alpha_p;

    const unsigned short* qrow = qk + (size_t)(b * LL + q0 + w * 16 + l15) * 1024 + hh * DH;
    s16x8 qf0 = *(const s16x8*)(qrow + lg * 8);
    s16x8 qf1 = *(const s16x8*)(qrow + 32 + lg * 8);
    #pragma unroll
    for (int j = 0; j < 8; ++j) {
        qf0[j] = (short)f2bf(bf2f((unsigned short)qf0[j]) * 0.125f);
        qf1[j] = (short)f2bf(bf2f((unsigned short)qf1[j]) * 0.125f);
    }

    float cm1[4], cp1[4];
    #pragma unroll
    for (int r2 = 0; r2 < 4; ++r2) {
        int qi = q0 + w * 16 + lg * 4 + r2;
        cm1[r2] = 0.f; cp1[r2] = 0.f;
        if (qi >= 1 && qi < len) {
            int src = (qi == 1 || qi == LL - 1) ? qi : qi - 1;
            cm1[r2] = alpha * c_local[(size_t)b * LL + src];
        }
        if (qi + 1 < LL && qi < len)
            cp1[r2] = alpha * c_local[(size_t)b * LL + qi + 1];
    }
    bool need_sink = (sink_blk && w == 0 && lg == 0);

    float m_run[4], l_run[4];
    f32x4 accO[4] = {};
    #pragma unroll
    for (int r2 = 0; r2 < 4; ++r2) { m_run[r2] = -1e30f; l_run[r2] = 0.f; }

    int sr = t >> 3, sc8 = (t & 7) * 8;
    const unsigned short* kbase = qk + (size_t)(b * LL) * 1024 + 512 + hh * DH;
    const unsigned short* vbase = Vt + (size_t)(hh * DH) * MM + b * LL;

    uint4 pk0 = *(const uint4*)(kbase + (size_t)sr * 1024 + sc8);
    uint4 pk1 = *(const uint4*)(kbase + (size_t)(sr + 32) * 1024 + sc8);
    uint4 pv0 = *(const uint4*)(vbase + (size_t)sr * MM + sc8);
    uint4 pv1 = *(const uint4*)(vbase + (size_t)(sr + 32) * MM + sc8);
    *(uint4*)&Ks[0][sr * SK + sc8]         = pk0;
    *(uint4*)&Ks[0][(sr + 32) * SK + sc8]  = pk1;
    *(uint4*)&Vts[0][sr * SK + sc8]        = pv0;
    *(uint4*)&Vts[0][(sr + 32) * SK + sc8] = pv1;
    __syncthreads();

    int cur = 0;
    for (int kt = 0; kt < nt; ++kt) {
        int k0 = kt * 64;
        bool pre = (kt + 1 < nt);
        if (pre) {
            int kn = k0 + 64;
            pk0 = *(const uint4*)(kbase + (size_t)(kn + sr) * 1024 + sc8);
            pk1 = *(const uint4*)(kbase + (size_t)(kn + sr + 32) * 1024 + sc8);
            pv0 = *(const uint4*)(vbase + (size_t)sr * MM + kn + sc8);
            pv1 = *(const uint4*)(vbase + (size_t)(sr + 32) * MM + kn + sc8);
        }

        f32x4 accS[4] = {};
        #pragma unroll
        for (int ct = 0; ct < 4; ++ct) {
            s16x8 kf0 = *(const s16x8*)&Ks[cur][(ct * 16 + l15) * SK + lg * 8];
            s16x8 kf1 = *(const s16x8*)&Ks[cur][(ct * 16 + l15) * SK + 32 + lg * 8];
            accS[ct] = __builtin_amdgcn_mfma_f32_16x16x32_bf16(qf0, kf0, accS[ct], 0, 0, 0);
            accS[ct] = __builtin_amdgcn_mfma_f32_16x16x32_bf16(qf1, kf1, accS[ct], 0, 0, 0);
        }

        float m4[4] = { -1e30f, -1e30f, -1e30f, -1e30f };
        bool slow = sink_blk || (kt >= kt0 - 1 && kt <= kt0 + 1) || (k0 + 64 > len);
        if (!slow) {
            #pragma unroll
            for (int ct = 0; ct < 4; ++ct)
                #pragma unroll
                for (int r2 = 0; r2 < 4; ++r2)
                    m4[r2] = fmaxf(m4[r2], accS[ct][r2]);
        } else if (k0 + 64 <= len) {
            #pragma unroll
            for (int ct = 0; ct < 4; ++ct) {
                int k = k0 + ct * 16 + l15;
                float sink_ct = need_sink ? srow[(size_t)b * LL + k] : 0.f;
                #pragma unroll
                for (int r2 = 0; r2 < 4; ++r2) {
                    int qi = q0 + w * 16 + lg * 4 + r2;
                    float v = accS[ct][r2];
                    if (k == qi - 1) v += cm1[r2];
                    else if (k == qi + 1) v += cp1[r2];
                    if (r2 == 0) v += sink_ct;
                    accS[ct][r2] = v;
                    m4[r2] = fmaxf(m4[r2], v);
                }
            }
        } else {
            #pragma unroll
            for (int ct = 0; ct < 4; ++ct) {
                int k = k0 + ct * 16 + l15;
                bool maskk = (k >= len);
                float sink_ct = need_sink ? srow[(size_t)b * LL + k] : 0.f;
                #pragma unroll
                for (int r2 = 0; r2 < 4; ++r2) {
                    int qi = q0 + w * 16 + lg * 4 + r2;
                    float v = accS[ct][r2];
                    if (k == qi - 1) v += cm1[r2];
                    else if (k == qi + 1 && !maskk) v += cp1[r2];
                    if (r2 == 0) v += sink_ct;
                    if (maskk) v -= 10000.f;
                    accS[ct][r2] = v;
                    m4[r2] = fmaxf(m4[r2], v);
                }
            }
        }

        #pragma unroll
        for (int r2 = 0; r2 < 4; ++r2) {
            #pragma unroll
            for (int msk = 1; msk < 16; msk <<= 1) m4[r2] = fmaxf(m4[r2], __shfl_xor(m4[r2], msk));
            float mnew = fmaxf(m_run[r2], m4[r2]);
            float scl = __expf(m_run[r2] - mnew);
            m_run[r2] = mnew;
            float rowsum = 0.f;
            #pragma unroll
            for (int ct = 0; ct < 4; ++ct) {
                float p = __expf(accS[ct][r2] - mnew);
                rowsum += p;
                Psb[(w * 16 + lg * 4 + r2) * SPB + ct * 16 + l15] = f2bf(p);
            }
            #pragma unroll
            for (int msk = 1; msk < 16; msk <<= 1) rowsum += __shfl_xor(rowsum, msk);
            l_run[r2] = l_run[r2] * scl + rowsum;
            #pragma unroll
            for (int dt = 0; dt < 4; ++dt) accO[dt][r2] *= scl;
        }

        #pragma unroll
        for (int kk = 0; kk < 2; ++kk) {
            s16x8 pf = *(const s16x8*)&Psb[(w * 16 + l15) * SPB + kk * 32 + lg * 8];
            #pragma unroll
            for (int dt = 0; dt < 4; ++dt) {
                s16x8 vf = *(const s16x8*)&Vts[cur][(dt * 16 + l15) * SK + kk * 32 + lg * 8];
                accO[dt] = __builtin_amdgcn_mfma_f32_16x16x32_bf16(pf, vf, accO[dt], 0, 0, 0);
            }
        }

        if (pre) {
            int nxt = cur ^ 1;
            *(uint4*)&Ks[nxt][sr * SK + sc8]         = pk0;
            *(uint4*)&Ks[nxt][(sr + 32) * SK + sc8]  = pk1;
            *(uint4*)&Vts[nxt][sr * SK + sc8]        = pv0;
            *(uint4*)&Vts[nxt][(sr + 32) * SK + sc8] = pv1;
        }
        __syncthreads();
        cur ^= 1;
    }

    #pragma unroll
    for (int r2 = 0; r2 < 4; ++r2) {
        float inv = 1.f / l_run[r2];
        int qi = q0 + w * 16 + lg * 4 + r2;
        #pragma unroll
        for (int dt = 0; dt < 4; ++dt)
            o[(size_t)(b * LL + qi) * DD + hh * DH + dt * 16 + l15] = f2bf(accO[dt][r2] * inv);
    }
}

// ------ embed epilogue: h(bf16) += LN(e_pre) + mask?0:gain*LN(cpe_pre); writes layer-0 LN stats ------
__global__ __launch_bounds__(256) void embed_ep_kernel(
    const float* __restrict__ cpe_pre, const float* __restrict__ e_pre,
    const int* __restrict__ lengths,
    const float* __restrict__ cpe_g, const float* __restrict__ cpe_lb,
    const float* __restrict__ de_lng, const float* __restrict__ de_lnb,
    const float* __restrict__ gain_p, unsigned short* __restrict__ h,
    float* __restrict__ stats0)
{
    int row = blockIdx.x;
    int b = row >> 10, l = row & 1023;
    int t = threadIdx.x;
    __shared__ float red[32];
    const float* cp = cpe_pre + (size_t)row * DD;
    float v0 = cp[t], v1 = cp[t + 256];
    float e0 = e_pre[(size_t)b * DD + t], e1 = e_pre[(size_t)b * DD + t + 256];
    float s  = v0 + v1, ss  = v0 * v0 + v1 * v1;
    float s2 = e0 + e1, ss2 = e0 * e0 + e1 * e1;
    float rs  = wave_reduce_sum(s),  rss  = wave_reduce_sum(ss);
    float rs2 = wave_reduce_sum(s2), rss2 = wave_reduce_sum(ss2);
    int lane = t & 63, w = t >> 6;
    if (lane == 0) { red[w] = rs; red[8 + w] = rss; red[16 + w] = rs2; red[24 + w] = rss2; }
    __syncthreads();
    float mean = 0.f, msq = 0.f, mean_e = 0.f, msq_e = 0.f;
    #pragma unroll
    for (int i = 0; i < 4; ++i) {
        mean += red[i]; msq += red[8 + i];
        mean_e += red[16 + i]; msq_e += red[24 + i];
    }
    mean *= (1.0f / DD); msq *= (1.0f / DD);
    mean_e *= (1.0f / DD); msq_e *= (1.0f / DD);
    float rstd   = rsqrtf(msq - mean * mean + 1e-5f);
    float rstd_e = rsqrtf(msq_e - mean_e * mean_e + 1e-5f);
    float eln0 = (e0 - mean_e) * rstd_e * de_lng[t]       + de_lnb[t];
    float eln1 = (e1 - mean_e) * rstd_e * de_lng[t + 256] + de_lnb[t + 256];
    bool maskp = (l >= lengths[b]);
    float gain = *gain_p;
    float pe0 = maskp ? 0.f : gain * ((v0 - mean) * rstd * cpe_g[t] + cpe_lb[t]);
    float pe1 = maskp ? 0.f : gain * ((v1 - mean) * rstd * cpe_g[t + 256] + cpe_lb[t + 256]);
    size_t o0 = (size_t)row * DD + t;
    size_t o1 = (size_t)row * DD + t + 256;
    float hn0 = bf2f(h[o0]) + eln0 + pe0;
    float hn1 = bf2f(h[o1]) + eln1 + pe1;
    h[o0] = f2bf(hn0);
    h[o1] = f2bf(hn1);
    // stats of the new h row (for layer-0 fused LN)
    float s3 = hn0 + hn1, ss3 = hn0 * hn0 + hn1 * hn1;
    float rs3 = wave_reduce_sum(s3), rss3 = wave_reduce_sum(ss3);
    __syncthreads();
    if (lane == 0) { red[w] = rs3; red[8 + w] = rss3; }
    __syncthreads();
    if (t == 0) {
        float a = red[0] + red[1] + red[2] + red[3];
        float q = red[8] + red[9] + red[10] + red[11];
        stats0[2 * row] = a;
        stats0[2 * row + 1] = q;
    }
}

// ---------------- LayerNorm (bf16 in, f32 out — final) ----------------
__global__ __launch_bounds__(256) void ln_kernel(
    const unsigned short* __restrict__ in, float* __restrict__ out,
    const float* __restrict__ g, const float* __restrict__ bta)
{
    int row = blockIdx.x; int t = threadIdx.x;
    __shared__ float red[16];
    const unsigned short* xr = in + (size_t)row * DD;
    ushort2 u = ((const ushort2*)xr)[t];
    float vx = bf2f(u.x), vy = bf2f(u.y);
    float s = vx + vy, ss = vx * vx + vy * vy;
    float rs = wave_reduce_sum(s), rss = wave_reduce_sum(ss);
    int lane = t & 63, w = t >> 6;
    if (lane == 0) { red[w] = rs; red[8 + w] = rss; }
    __syncthreads();
    float mean = 0.f, msq = 0.f;
    #pragma unroll
    for (int i = 0; i < 4; ++i) { mean += red[i]; msq += red[8 + i]; }
    mean *= (1.0f / DD); msq *= (1.0f / DD);
    float rstd = rsqrtf(msq - mean * mean + 1e-5f);
    float2 gg = ((const float2*)g)[t], bb = ((const float2*)bta)[t];
    float2 o;
    o.x = (vx - mean) * rstd * gg.x + bb.x;
    o.y = (vy - mean) * rstd * gg.y + bb.y;
    ((float2*)(out + (size_t)row * DD))[t] = o;
}

extern "C" void kernel_launch(void* const* d_in, const int* in_sizes, int n_in,
                              void* d_out, int out_size, void* d_ws, size_t ws_size,
                              hipStream_t stream)
{
    const float* x          = (const float*)d_in[0];
    const int*   lengths    = (const int*)  d_in[1];
    const float* input_delay= (const float*)d_in[2];
    const float* c_local    = (const float*)d_in[3];
    const float* c_sink     = (const float*)d_in[4];
    const float* in_w       = (const float*)d_in[5];
    const float* in_b       = (const float*)d_in[6];
    const float* de_w1      = (const float*)d_in[7];
    const float* de_b1      = (const float*)d_in[8];
    const float* de_w2      = (const float*)d_in[9];
    const float* de_b2      = (const float*)d_in[10];
    const float* de_ln_g    = (const float*)d_in[11];
    const float* de_ln_b    = (const float*)d_in[12];
    const float* cpe_w      = (const float*)d_in[13];
    const float* cpe_b      = (const float*)d_in[14];
    const float* cpe_ln_g   = (const float*)d_in[15];
    const float* cpe_ln_b   = (const float*)d_in[16];
    const float* gain       = (const float*)d_in[17];
    const float* alpha      = (const float*)d_in[18];
    const float* beta       = (const float*)d_in[19];
    const float* floorp     = (const float*)d_in[20];
    const float* gammap     = (const float*)d_in[21];
    const float* inproj_w   = (const float*)d_in[22];
    const float* inproj_b   = (const float*)d_in[23];
    const float* outproj_w  = (const float*)d_in[24];
    const float* outproj_b  = (const float*)d_in[25];
    const float* ln1_g      = (const float*)d_in[26];
    const float* ln1_b      = (const float*)d_in[27];
    const float* ln2_g      = (const float*)d_in[28];
    const float* ln2_b      = (const float*)d_in[29];
    const float* ff_w1      = (const float*)d_in[30];
    const float* ff_b1      = (const float*)d_in[31];
    const float* ff_w2      = (const float*)d_in[32];
    const float* ff_b2      = (const float*)d_in[33];
    const float* out_ln_g   = (const float*)d_in[34];
    const float* out_ln_b   = (const float*)d_in[35];

    char* base = (char*)d_ws;
    unsigned short* h    = (unsigned short*)base;                     // 4 MB (bf16 residual)
    unsigned short* ao   = (unsigned short*)(base + 8u*1024*1024);    // 4 MB (attn out)
    char* bigb          = base + 12u*1024*1024;                       // 16 MB shared region
    unsigned short* qkb  = (unsigned short*)bigb;                     // 8 MB (attn phase: Q,K)
    unsigned short* vtb  = (unsigned short*)(bigb + 12u*1024*1024);   // 4 MB (attn phase: V^T)
    unsigned short* ffb  = (unsigned short*)bigb;                     // 16 MB (FF phase)
    unsigned short* Zb   = (unsigned short*)bigb;                     // 4.7 MB (embed phase)
    unsigned short* x_bf = (unsigned short*)(bigb + 5u*1024*1024);    // 0.5 MB
    float* cpe_pre       = (float*)(bigb + 8u*1024*1024);             // 8 MB
    unsigned short* w_inproj  = (unsigned short*)(base + 28u*1024*1024);
    unsigned short* w_outproj = w_inproj  + (size_t)3*1536*512;
    unsigned short* w_ff1     = w_outproj + (size_t)3*512*512;
    unsigned short* w_ff2     = w_ff1     + (size_t)3*2048*512;
    unsigned short* w_in      = w_ff2     + (size_t)3*512*2048;
    unsigned short* w_cpe     = w_in      + (size_t)512*64;
    float* e_pre              = (float*)(w_cpe + (size_t)512*FEATP);
    float* srow               = e_pre + (size_t)BB*DD;
    float* zbuf               = srow + (size_t)BB*LL;                 // stats + c1/c2 region
    float* stats_ln1          = zbuf;                                 // [4][4096][2]
    float* stats_ln2          = stats_ln1 + (size_t)4 * MM * 2;       // [3][4096][2]
    float* c1_in              = stats_ln2 + (size_t)3 * MM * 2;       // [3*1536]
    float* c2_in              = c1_in + 3 * 1536;
    float* c1_ff              = c2_in + 3 * 1536;                     // [3*2048]
    float* c2_ff              = c1_ff + 3 * 2048;

    prologue_kernel<<<LL + 256 + 64, 256, 0, stream>>>(
        c_local, c_sink, lengths, beta, floorp, gammap, Zb, srow,
        x, in_w, cpe_w, x_bf, w_in, w_cpe,
        input_delay, de_w1, de_b1, de_w2, de_b2, e_pre, zbuf);

    gemm_pre_dual<<<2048, 256, 0, stream>>>(x_bf, w_in, in_b, h, Zb, w_cpe, cpe_b, cpe_pre,
                                            inproj_w, outproj_w, ff_w1, ff_w2,
                                            w_inproj, w_outproj, w_ff1, w_ff2,
                                            ln1_g, ln1_b, ln2_g, ln2_b,
                                            c1_in, c2_in, c1_ff, c2_ff);
    embed_ep_kernel<<<MM, 256, 0, stream>>>(cpe_pre, e_pre, lengths, cpe_ln_g, cpe_ln_b,
                                            de_ln_g, de_ln_b, gain, h, stats_ln1);

    for (int i = 0; i < NLAYER; ++i) {
        const unsigned short* wqk = w_inproj + (size_t)i * 1536 * 512;          // folded Q,K rows [0,1024)
        const unsigned short* wv  = wqk + (size_t)1024 * 512;                   // folded V rows [1024,1536)
        float* st1  = stats_ln1 + (size_t)i * MM * 2;
        float* st2  = stats_ln2 + (size_t)i * MM * 2;
        float* st1n = stats_ln1 + (size_t)(i + 1) * MM * 2;
        const float* c1L = c1_in + (size_t)i * 1536;
        const float* c2L = c2_in + (size_t)i * 1536;
        const float* c1F = c1_ff + (size_t)i * 2048;
        const float* c2F = c2_ff + (size_t)i * 2048;

        gemm_qkv_dual<<<1536, 256, 0, stream>>>(h, wqk, inproj_b + (size_t)i * 1536, qkb,
                                                wv, inproj_b + (size_t)i * 1536 + 1024, vtb,
                                                c1L, c2L, c1L + 1024, c2L + 1024, st1);
        attn_mfma<<<512, 256, 0, stream>>>(qkb, vtb, c_local, srow, lengths, alpha, ao);
        gemm_t<64, 64, 2, 2, 2, 2><<<dim3(DD / 64, MM / 64), 256, 0, stream>>>(
            ao, w_outproj + (size_t)i * 512 * 512, outproj_b + (size_t)i * DD,
            h, nullptr, h, MM, DD, DD, nullptr, nullptr, nullptr, st2);
        gemm_t<128, 128, 4, 4, 2, 7><<<dim3(DFF / 128, MM / 128), 256, 0, stream>>>(
            h, w_ff1 + (size_t)i * 2048 * 512, ff_b1 + (size_t)i * DFF,
            nullptr, nullptr, ffb, MM, DFF, DD, c1F, c2F, st2, nullptr);
        gemm_t<64, 64, 2, 2, 2, 2><<<dim3(DD / 64, MM / 64), 256, 0, stream>>>(
            ffb, w_ff2 + (size_t)i * 512 * 2048, ff_b2 + (size_t)i * DD,
            h, nullptr, h, MM, DD, DFF, nullptr, nullptr, nullptr, st1n);
    }
    ln_kernel<<<MM, 256, 0, stream>>>(h, (float*)d_out, out_ln_g, out_ln_b);
}

// Round 25
// 390.012 us; speedup vs baseline: 1.1799x; 1.1799x over previous
//
#include <hip/hip_runtime.h>
#include <math.h>

#define BB 4
#define LL 1024
#define DIN 64
#define DD 512
#define HH 8
#define DH 64
#define NLAYER 3
#define DFF 2048
#define FEAT 530
#define FEATP 576
#define MM 4096

typedef float f32x4 __attribute__((ext_vector_type(4)));
typedef short s16x8 __attribute__((ext_vector_type(8)));

__device__ __forceinline__ unsigned short f2bf(float f) {
    unsigned int u = __float_as_uint(f);
    u += 0x7fffu + ((u >> 16) & 1u);
    return (unsigned short)(u >> 16);
}
__device__ __forceinline__ float bf2f(unsigned short u) {
    return __uint_as_float(((unsigned int)u) << 16);
}
__device__ __forceinline__ float gelu_exact(float x) {
    return 0.5f * x * (1.0f + erff(x * 0.7071067811865475f));
}
__device__ __forceinline__ float wave_reduce_sum(float v) {
    #pragma unroll
    for (int o = 32; o; o >>= 1) v += __shfl_down(v, o);
    return v;
}
__device__ __forceinline__ void gload16(const unsigned short* g, unsigned short* l) {
    __builtin_amdgcn_global_load_lds(
        (const __attribute__((address_space(1))) unsigned int*)g,
        (__attribute__((address_space(3))) unsigned int*)l, 16, 0, 0);
}
__device__ __forceinline__ void cvt16(const float* src, unsigned short* dst) {
    float4 f0 = ((const float4*)src)[0];
    float4 f1 = ((const float4*)src)[1];
    float4 f2 = ((const float4*)src)[2];
    float4 f3 = ((const float4*)src)[3];
    ushort4 o0, o1, o2, o3;
    o0.x = f2bf(f0.x); o0.y = f2bf(f0.y); o0.z = f2bf(f0.z); o0.w = f2bf(f0.w);
    o1.x = f2bf(f1.x); o1.y = f2bf(f1.y); o1.z = f2bf(f1.z); o1.w = f2bf(f1.w);
    o2.x = f2bf(f2.x); o2.y = f2bf(f2.y); o2.z = f2bf(f2.z); o2.w = f2bf(f2.w);
    o3.x = f2bf(f3.x); o3.y = f2bf(f3.y); o3.z = f2bf(f3.z); o3.w = f2bf(f3.w);
    ((ushort4*)dst)[0] = o0;
    ((ushort4*)dst)[1] = o1;
    ((ushort4*)dst)[2] = o2;
    ((ushort4*)dst)[3] = o3;
}

// ------------- small prologue: PE/z (1024) | small converts (256) | delay matvec (64) -------------
__global__ __launch_bounds__(256) void prologue_kernel(
    const float* __restrict__ c_local, const float* __restrict__ c_sink,
    const int* __restrict__ lengths,
    const float* __restrict__ beta_p, const float* __restrict__ floor_p,
    const float* __restrict__ gamma_p,
    unsigned short* __restrict__ Z, float* __restrict__ srow,
    const float* __restrict__ x, const float* __restrict__ in_w,
    const float* __restrict__ cpe_w,
    unsigned short* __restrict__ x_bf, unsigned short* __restrict__ w_in,
    unsigned short* __restrict__ w_cpe,
    const float* __restrict__ delay, const float* __restrict__ de_w1, const float* __restrict__ de_b1,
    const float* __restrict__ de_w2, const float* __restrict__ de_b2,
    float* __restrict__ e_pre)
{
    int blk = blockIdx.x;
    int t = threadIdx.x;

    if (blk < LL) {
        int l = blk;
        for (int d = t; d < DD; d += 256) {
            int i = d >> 1;
            float dv = expf((float)(2 * i) * (-0.017988946135618352f)); // -ln(1e4)/512
            float ang = (float)l * dv;
            unsigned short pv = f2bf((d & 1) ? cosf(ang) : sinf(ang));
            #pragma unroll
            for (int bb = 0; bb < 4; ++bb)
                Z[(size_t)(bb * LL + l) * FEATP + d] = pv;
        }
        {
            int bb = t >> 6, j = t & 63;
            float cl = c_local[(size_t)bb * LL + l]; cl = fminf(fmaxf(cl, 0.f), 1.f);
            float cs = c_sink [(size_t)bb * LL + l]; cs = fminf(fmaxf(cs, 0.f), 1.f);
            float v = 0.f;
            if (j == 0) v = cl;
            else if (j == 1) v = cs;
            else if (j < 10)  { float c = (float)(j - 2) * (1.0f / 7.0f);  float df = (cl - c) / 0.200001f; v = expf(-0.5f * df * df); }
            else if (j < 18)  { float c = (float)(j - 10) * (1.0f / 7.0f); float df = (cs - c) / 0.200001f; v = expf(-0.5f * df * df); }
            Z[(size_t)(bb * LL + l) * FEATP + 512 + j] = (j < 18) ? f2bf(v) : 0;
            if (j == 32) {
                float sv = (*beta_p) * ((*floor_p) + (1.f - (*floor_p)) * powf(cs + 1e-6f, *gamma_p));
                srow[bb * LL + l] = (l < lengths[bb]) ? sv : 0.f;
            }
        }
    } else if (blk < LL + 256) {
        const int N0s = MM * DIN;
        const int N1s = N0s + 512 * 64;
        const int NCHs = N1s / 16;
        int vb = blk - LL;
        for (int c = vb * 256 + t; c < NCHs; c += 256 * 256) {
            int i = c * 16;
            if (i < N0s) cvt16(x + i, x_bf + i);
            else         cvt16(in_w + (i - N0s), w_in + (i - N0s));
        }
        for (int j = vb * 256 + t; j < 512 * FEATP; j += 256 * 256) {
            int r = j / FEATP, c2 = j - r * FEATP;
            w_cpe[j] = (c2 < FEAT) ? f2bf(cpe_w[(size_t)r * FEAT + c2]) : 0;
        }
    } else {
        __shared__ float g1[DD];
        int idx = blk - (LL + 256);
        int b  = idx >> 4;
        int r0 = (idx & 15) * 32;
        float d0 = delay[b];
        g1[t]       = gelu_exact(d0 * de_w1[t]       + de_b1[t]);
        g1[t + 256] = gelu_exact(d0 * de_w1[t + 256] + de_b1[t + 256]);
        __syncthreads();
        int r = t >> 3, c = t & 7;
        const float* wr = de_w2 + (size_t)(r0 + r) * DD + c * 64;
        const float* gc = g1 + c * 64;
        float s = 0.f;
        #pragma unroll
        for (int j = 0; j < 64; j += 4) {
            float4 a4 = *(const float4*)(wr + j);
            s += a4.x * gc[j] + a4.y * gc[j+1] + a4.z * gc[j+2] + a4.w * gc[j+3];
        }
        s += __shfl_xor(s, 1);
        s += __shfl_xor(s, 2);
        s += __shfl_xor(s, 4);
        if (c == 0) e_pre[(size_t)b * DD + r0 + r] = s + de_b2[r0 + r];
    }
}

// ---- GEMM body (BK=64, dbuf LDS, runtime mode) ----
// MODE 0: f32 out ; 1: bf16 out ; 2: bf16 out = acc+bias+bf16 resid ;
// 3: bf16 gelu ; 4: bf16 out, bias by ROW
template<int BM, int BN, int FM, int FN, int WGN>
__device__ __forceinline__ void gemm_body(
    const unsigned short* __restrict__ A, const unsigned short* __restrict__ W,
    const float* __restrict__ bias, const unsigned short* __restrict__ residb,
    float* __restrict__ outf, unsigned short* __restrict__ outb,
    int M, int N, int K, int mode, int bm, int bn,
    unsigned short* As, unsigned short* Ws)
{
    int t = threadIdx.x;
    int lane = t & 63, wid = t >> 6;
    int wr = wid / WGN, wc = wid % WGN;
    int l15 = lane & 15, lg = lane >> 4;
    int sr = lane >> 3;
    int sc = ((lane & 7) ^ sr) * 8;
    int ph0 = (lg ^ (l15 & 7)) * 8;
    int ph1 = ((lg + 4) ^ (l15 & 7)) * 8;

    f32x4 acc[FM][FN] = {};
    int nk = K >> 6;

    auto stage = [&](int buf, int ks) {
        int kb = ks * 64;
        #pragma unroll
        for (int i = 0; i < BM / 32; ++i) {
            int row = wid * (BM / 4) + i * 8 + sr;
            gload16(A + (size_t)(bm + row) * K + kb + sc, &As[(size_t)buf * BM * 64 + (wid * (BM / 4) + i * 8) * 64]);
        }
        #pragma unroll
        for (int i = 0; i < BN / 32; ++i) {
            int row = wid * (BN / 4) + i * 8 + sr;
            gload16(W + (size_t)(bn + row) * K + kb + sc, &Ws[(size_t)buf * BN * 64 + (wid * (BN / 4) + i * 8) * 64]);
        }
    };

    stage(0, 0);
    __syncthreads();

    int cur = 0;
    for (int ks = 0; ks < nk; ++ks) {
        if (ks + 1 < nk) stage(cur ^ 1, ks + 1);
        s16x8 af0[FM], af1[FM], wf0[FN], wf1[FN];
        #pragma unroll
        for (int mi = 0; mi < FM; ++mi) {
            int row = wr * FM * 16 + mi * 16 + l15;
            af0[mi] = *(const s16x8*)&As[(size_t)cur * BM * 64 + row * 64 + ph0];
            af1[mi] = *(const s16x8*)&As[(size_t)cur * BM * 64 + row * 64 + ph1];
        }
        #pragma unroll
        for (int ni = 0; ni < FN; ++ni) {
            int row = wc * FN * 16 + ni * 16 + l15;
            wf0[ni] = *(const s16x8*)&Ws[(size_t)cur * BN * 64 + row * 64 + ph0];
            wf1[ni] = *(const s16x8*)&Ws[(size_t)cur * BN * 64 + row * 64 + ph1];
        }
        #pragma unroll
        for (int mi = 0; mi < FM; ++mi)
            #pragma unroll
            for (int ni = 0; ni < FN; ++ni) {
                acc[mi][ni] = __builtin_amdgcn_mfma_f32_16x16x32_bf16(af0[mi], wf0[ni], acc[mi][ni], 0, 0, 0);
                acc[mi][ni] = __builtin_amdgcn_mfma_f32_16x16x32_bf16(af1[mi], wf1[ni], acc[mi][ni], 0, 0, 0);
            }
        __syncthreads();
        cur ^= 1;
    }

    int rbase = (lane >> 4) * 4;
    #pragma unroll
    for (int mi = 0; mi < FM; ++mi) {
        #pragma unroll
        for (int ni = 0; ni < FN; ++ni) {
            int n = bn + wc * FN * 16 + ni * 16 + l15;
            float bzc = (mode == 4) ? 0.f : bias[n];
            #pragma unroll
            for (int r2 = 0; r2 < 4; ++r2) {
                int m = bm + wr * FM * 16 + mi * 16 + rbase + r2;
                float v = acc[mi][ni][r2] + ((mode == 4) ? bias[m] : bzc);
                size_t o = (size_t)m * N + n;
                if (mode == 0)      outf[o] = v;
                else if (mode == 1) outb[o] = f2bf(v);
                else if (mode == 2) outb[o] = f2bf(v + bf2f(residb[o]));
                else if (mode == 3) outb[o] = f2bf(gelu_exact(v));
                else                outb[o] = f2bf(v);
            }
        }
    }
}

// ---- standalone templated GEMM ----
template<int BM, int BN, int FM, int FN, int WGN, int MODE>
__global__ __launch_bounds__(256) void gemm_t(
    const unsigned short* __restrict__ A, const unsigned short* __restrict__ W,
    const float* __restrict__ bias, const unsigned short* __restrict__ residb,
    float* __restrict__ outf, unsigned short* __restrict__ outb,
    int M, int N, int K)
{
    __shared__ __align__(16) unsigned short As[2 * BM * 64];
    __shared__ __align__(16) unsigned short Ws[2 * BN * 64];
    gemm_body<BM, BN, FM, FN, WGN>(A, W, bias, residb, outf, outb, M, N, K, MODE,
                                   blockIdx.y * BM, blockIdx.x * BN, As, Ws);
}

// ---- dual dispatch: h0 GEMM (512, bf16 out) + cpe GEMM (512) + big-weight converts (1024) ----
__global__ __launch_bounds__(256) void gemm_pre_dual(
    const unsigned short* __restrict__ x_bf, const unsigned short* __restrict__ w_in,
    const float* __restrict__ in_b, unsigned short* __restrict__ h,
    const unsigned short* __restrict__ Zb, const unsigned short* __restrict__ w_cpe,
    const float* __restrict__ cpe_b, float* __restrict__ cpe_pre,
    const float* __restrict__ inproj_w, const float* __restrict__ outproj_w,
    const float* __restrict__ ff_w1, const float* __restrict__ ff_w2,
    unsigned short* __restrict__ w_inproj, unsigned short* __restrict__ w_outproj,
    unsigned short* __restrict__ w_ff1, unsigned short* __restrict__ w_ff2)
{
    __shared__ __align__(16) unsigned short As[2 * 64 * 64];
    __shared__ __align__(16) unsigned short Ws[2 * 64 * 64];
    int id = blockIdx.x;
    if (id < 512) {
        gemm_body<64, 64, 2, 2, 2>(x_bf, w_in, in_b, nullptr, nullptr, h,
                                   MM, DD, DIN, 1, (id >> 3) * 64, (id & 7) * 64, As, Ws);
    } else if (id < 1024) {
        id -= 512;
        gemm_body<64, 64, 2, 2, 2>(Zb, w_cpe, cpe_b, nullptr, cpe_pre, nullptr,
                                   MM, DD, FEATP, 0, (id >> 3) * 64, (id & 7) * 64, As, Ws);
    } else {
        const int B0 = 3 * 1536 * 512;
        const int B1 = B0 + 3 * 512 * 512;
        const int B2 = B1 + 3 * 2048 * 512;
        const int B3 = B2 + 3 * 512 * 2048;
        const int NCH = B3 / 16;
        int vb = id - 1024;
        int t = threadIdx.x;
        for (int c = vb * 256 + t; c < NCH; c += 1024 * 256) {
            int i = c * 16;
            if (i < B0)      cvt16(inproj_w + i,         w_inproj + i);
            else if (i < B1) cvt16(outproj_w + (i - B0), w_outproj + (i - B0));
            else if (i < B2) cvt16(ff_w1 + (i - B1),     w_ff1 + (i - B1));
            else             cvt16(ff_w2 + (i - B2),     w_ff2 + (i - B2));
        }
    }
}

// ---- dual dispatch: QK GEMM (1024 blocks) + V^T GEMM (512 blocks) ----
__global__ __launch_bounds__(256) void gemm_qkv_dual(
    const unsigned short* __restrict__ act1,
    const unsigned short* __restrict__ wqk, const float* __restrict__ qk_bias,
    unsigned short* __restrict__ qkb,
    const unsigned short* __restrict__ wv, const float* __restrict__ v_bias,
    unsigned short* __restrict__ vtb)
{
    __shared__ __align__(16) unsigned short As[2 * 64 * 64];
    __shared__ __align__(16) unsigned short Ws[2 * 64 * 64];
    int id = blockIdx.x;
    if (id < 1024) {
        gemm_body<64, 64, 2, 2, 2>(act1, wqk, qk_bias, nullptr, nullptr, qkb,
                                   MM, 1024, DD, 1, (id >> 4) * 64, (id & 15) * 64, As, Ws);
    } else {
        id -= 1024;
        gemm_body<64, 64, 2, 2, 2>(wv, act1, v_bias, nullptr, nullptr, vtb,
                                   DD, MM, DD, 4, (id >> 6) * 64, (id & 63) * 64, As, Ws);
    }
}

// ------------- MFMA flash attention: natural block order (XCD-balanced), dbuf K/V -------------
#define SK 72
#define SPB 72
__global__ __launch_bounds__(256) void attn_mfma(
    const unsigned short* __restrict__ qk, const unsigned short* __restrict__ Vt,
    const float* __restrict__ c_local, const float* __restrict__ srow,
    const int* __restrict__ lengths,
    const float* __restrict__ alpha_p,
    unsigned short* __restrict__ o)
{
    __shared__ __align__(16) unsigned short Ks[2][64 * SK];
    __shared__ __align__(16) unsigned short Vts[2][64 * SK];
    __shared__ __align__(16) unsigned short Psb[64 * SPB];

    int id = blockIdx.x;
    int q0 = (id & 15) * 64;
    int hh = (id >> 4) & 7;
    int b  = id >> 7;

    int t  = threadIdx.x;
    int lane = t & 63, w = t >> 6;
    int l15 = lane & 15, lg = lane >> 4;
    int len = lengths[b];
    int nt = (len + 63) >> 6;
    int kt0 = q0 >> 6;
    bool sink_blk = (q0 == 0);
    const float alpha = *alpha_p;

    const unsigned short* qrow = qk + (size_t)(b * LL + q0 + w * 16 + l15) * 1024 + hh * DH;
    s16x8 qf0 = *(const s16x8*)(qrow + lg * 8);
    s16x8 qf1 = *(const s16x8*)(qrow + 32 + lg * 8);
    #pragma unroll
    for (int j = 0; j < 8; ++j) {
        qf0[j] = (short)f2bf(bf2f((unsigned short)qf0[j]) * 0.125f);
        qf1[j] = (short)f2bf(bf2f((unsigned short)qf1[j]) * 0.125f);
    }

    float cm1[4], cp1[4];
    #pragma unroll
    for (int r2 = 0; r2 < 4; ++r2) {
        int qi = q0 + w * 16 + lg * 4 + r2;
        cm1[r2] = 0.f; cp1[r2] = 0.f;
        if (qi >= 1 && qi < len) {
            int src = (qi == 1 || qi == LL - 1) ? qi : qi - 1;
            cm1[r2] = alpha * c_local[(size_t)b * LL + src];
        }
        if (qi + 1 < LL && qi < len)
            cp1[r2] = alpha * c_local[(size_t)b * LL + qi + 1];
    }
    bool need_sink = (sink_blk && w == 0 && lg == 0);

    float m_run[4], l_run[4];
    f32x4 accO[4] = {};
    #pragma unroll
    for (int r2 = 0; r2 < 4; ++r2) { m_run[r2] = -1e30f; l_run[r2] = 0.f; }

    int sr = t >> 3, sc8 = (t & 7) * 8;
    const unsigned short* kbase = qk + (size_t)(b * LL) * 1024 + 512 + hh * DH;
    const unsigned short* vbase = Vt + (size_t)(hh * DH) * MM + b * LL;

    uint4 pk0 = *(const uint4*)(kbase + (size_t)sr * 1024 + sc8);
    uint4 pk1 = *(const uint4*)(kbase + (size_t)(sr + 32) * 1024 + sc8);
    uint4 pv0 = *(const uint4*)(vbase + (size_t)sr * MM + sc8);
    uint4 pv1 = *(const uint4*)(vbase + (size_t)(sr + 32) * MM + sc8);
    *(uint4*)&Ks[0][sr * SK + sc8]         = pk0;
    *(uint4*)&Ks[0][(sr + 32) * SK + sc8]  = pk1;
    *(uint4*)&Vts[0][sr * SK + sc8]        = pv0;
    *(uint4*)&Vts[0][(sr + 32) * SK + sc8] = pv1;
    __syncthreads();

    int cur = 0;
    for (int kt = 0; kt < nt; ++kt) {
        int k0 = kt * 64;
        bool pre = (kt + 1 < nt);
        if (pre) {
            int kn = k0 + 64;
            pk0 = *(const uint4*)(kbase + (size_t)(kn + sr) * 1024 + sc8);
            pk1 = *(const uint4*)(kbase + (size_t)(kn + sr + 32) * 1024 + sc8);
            pv0 = *(const uint4*)(vbase + (size_t)sr * MM + kn + sc8);
            pv1 = *(const uint4*)(vbase + (size_t)(sr + 32) * MM + kn + sc8);
        }

        f32x4 accS[4] = {};
        #pragma unroll
        for (int ct = 0; ct < 4; ++ct) {
            s16x8 kf0 = *(const s16x8*)&Ks[cur][(ct * 16 + l15) * SK + lg * 8];
            s16x8 kf1 = *(const s16x8*)&Ks[cur][(ct * 16 + l15) * SK + 32 + lg * 8];
            accS[ct] = __builtin_amdgcn_mfma_f32_16x16x32_bf16(qf0, kf0, accS[ct], 0, 0, 0);
            accS[ct] = __builtin_amdgcn_mfma_f32_16x16x32_bf16(qf1, kf1, accS[ct], 0, 0, 0);
        }

        float m4[4] = { -1e30f, -1e30f, -1e30f, -1e30f };
        bool slow = sink_blk || (kt >= kt0 - 1 && kt <= kt0 + 1) || (k0 + 64 > len);
        if (!slow) {
            #pragma unroll
            for (int ct = 0; ct < 4; ++ct)
                #pragma unroll
                for (int r2 = 0; r2 < 4; ++r2)
                    m4[r2] = fmaxf(m4[r2], accS[ct][r2]);
        } else if (k0 + 64 <= len) {
            #pragma unroll
            for (int ct = 0; ct < 4; ++ct) {
                int k = k0 + ct * 16 + l15;
                float sink_ct = need_sink ? srow[(size_t)b * LL + k] : 0.f;
                #pragma unroll
                for (int r2 = 0; r2 < 4; ++r2) {
                    int qi = q0 + w * 16 + lg * 4 + r2;
                    float v = accS[ct][r2];
                    if (k == qi - 1) v += cm1[r2];
                    else if (k == qi + 1) v += cp1[r2];
                    if (r2 == 0) v += sink_ct;
                    accS[ct][r2] = v;
                    m4[r2] = fmaxf(m4[r2], v);
                }
            }
        } else {
            #pragma unroll
            for (int ct = 0; ct < 4; ++ct) {
                int k = k0 + ct * 16 + l15;
                bool maskk = (k >= len);
                float sink_ct = need_sink ? srow[(size_t)b * LL + k] : 0.f;
                #pragma unroll
                for (int r2 = 0; r2 < 4; ++r2) {
                    int qi = q0 + w * 16 + lg * 4 + r2;
                    float v = accS[ct][r2];
                    if (k == qi - 1) v += cm1[r2];
                    else if (k == qi + 1 && !maskk) v += cp1[r2];
                    if (r2 == 0) v += sink_ct;
                    if (maskk) v -= 10000.f;
                    accS[ct][r2] = v;
                    m4[r2] = fmaxf(m4[r2], v);
                }
            }
        }

        #pragma unroll
        for (int r2 = 0; r2 < 4; ++r2) {
            #pragma unroll
            for (int msk = 1; msk < 16; msk <<= 1) m4[r2] = fmaxf(m4[r2], __shfl_xor(m4[r2], msk));
            float mnew = fmaxf(m_run[r2], m4[r2]);
            float scl = __expf(m_run[r2] - mnew);
            m_run[r2] = mnew;
            float rowsum = 0.f;
            #pragma unroll
            for (int ct = 0; ct < 4; ++ct) {
                float p = __expf(accS[ct][r2] - mnew);
                rowsum += p;
                Psb[(w * 16 + lg * 4 + r2) * SPB + ct * 16 + l15] = f2bf(p);
            }
            #pragma unroll
            for (int msk = 1; msk < 16; msk <<= 1) rowsum += __shfl_xor(rowsum, msk);
            l_run[r2] = l_run[r2] * scl + rowsum;
            #pragma unroll
            for (int dt = 0; dt < 4; ++dt) accO[dt][r2] *= scl;
        }

        #pragma unroll
        for (int kk = 0; kk < 2; ++kk) {
            s16x8 pf = *(const s16x8*)&Psb[(w * 16 + l15) * SPB + kk * 32 + lg * 8];
            #pragma unroll
            for (int dt = 0; dt < 4; ++dt) {
                s16x8 vf = *(const s16x8*)&Vts[cur][(dt * 16 + l15) * SK + kk * 32 + lg * 8];
                accO[dt] = __builtin_amdgcn_mfma_f32_16x16x32_bf16(pf, vf, accO[dt], 0, 0, 0);
            }
        }

        if (pre) {
            int nxt = cur ^ 1;
            *(uint4*)&Ks[nxt][sr * SK + sc8]         = pk0;
            *(uint4*)&Ks[nxt][(sr + 32) * SK + sc8]  = pk1;
            *(uint4*)&Vts[nxt][sr * SK + sc8]        = pv0;
            *(uint4*)&Vts[nxt][(sr + 32) * SK + sc8] = pv1;
        }
        __syncthreads();
        cur ^= 1;
    }

    #pragma unroll
    for (int r2 = 0; r2 < 4; ++r2) {
        float inv = 1.f / l_run[r2];
        int qi = q0 + w * 16 + lg * 4 + r2;
        #pragma unroll
        for (int dt = 0; dt < 4; ++dt)
            o[(size_t)(b * LL + qi) * DD + hh * DH + dt * 16 + l15] = f2bf(accO[dt][r2] * inv);
    }
}

// ------ embed epilogue: h(bf16) += LN(e_pre) + mask?0:gain*LN(cpe_pre) ------
__global__ __launch_bounds__(256) void embed_ep_kernel(
    const float* __restrict__ cpe_pre, const float* __restrict__ e_pre,
    const int* __restrict__ lengths,
    const float* __restrict__ cpe_g, const float* __restrict__ cpe_lb,
    const float* __restrict__ de_lng, const float* __restrict__ de_lnb,
    const float* __restrict__ gain_p, unsigned short* __restrict__ h)
{
    int row = blockIdx.x;
    int b = row >> 10, l = row & 1023;
    int t = threadIdx.x;
    __shared__ float red[32];
    const float* cp = cpe_pre + (size_t)row * DD;
    float v0 = cp[t], v1 = cp[t + 256];
    float e0 = e_pre[(size_t)b * DD + t], e1 = e_pre[(size_t)b * DD + t + 256];
    float s  = v0 + v1, ss  = v0 * v0 + v1 * v1;
    float s2 = e0 + e1, ss2 = e0 * e0 + e1 * e1;
    float rs  = wave_reduce_sum(s),  rss  = wave_reduce_sum(ss);
    float rs2 = wave_reduce_sum(s2), rss2 = wave_reduce_sum(ss2);
    int lane = t & 63, w = t >> 6;
    if (lane == 0) { red[w] = rs; red[8 + w] = rss; red[16 + w] = rs2; red[24 + w] = rss2; }
    __syncthreads();
    float mean = 0.f, msq = 0.f, mean_e = 0.f, msq_e = 0.f;
    #pragma unroll
    for (int i = 0; i < 4; ++i) {
        mean += red[i]; msq += red[8 + i];
        mean_e += red[16 + i]; msq_e += red[24 + i];
    }
    mean *= (1.0f / DD); msq *= (1.0f / DD);
    mean_e *= (1.0f / DD); msq_e *= (1.0f / DD);
    float rstd   = rsqrtf(msq - mean * mean + 1e-5f);
    float rstd_e = rsqrtf(msq_e - mean_e * mean_e + 1e-5f);
    float eln0 = (e0 - mean_e) * rstd_e * de_lng[t]       + de_lnb[t];
    float eln1 = (e1 - mean_e) * rstd_e * de_lng[t + 256] + de_lnb[t + 256];
    bool maskp = (l >= lengths[b]);
    float gain = *gain_p;
    float pe0 = maskp ? 0.f : gain * ((v0 - mean) * rstd * cpe_g[t] + cpe_lb[t]);
    float pe1 = maskp ? 0.f : gain * ((v1 - mean) * rstd * cpe_g[t + 256] + cpe_lb[t + 256]);
    size_t o0 = (size_t)row * DD + t;
    size_t o1 = (size_t)row * DD + t + 256;
    h[o0] = f2bf(bf2f(h[o0]) + eln0 + pe0);
    h[o1] = f2bf(bf2f(h[o1]) + eln1 + pe1);
}

// ---------------- LayerNorm (bf16 in, f32 out — final) ----------------
__global__ __launch_bounds__(256) void ln_kernel(
    const unsigned short* __restrict__ in, float* __restrict__ out,
    const float* __restrict__ g, const float* __restrict__ bta)
{
    int row = blockIdx.x; int t = threadIdx.x;
    __shared__ float red[16];
    const unsigned short* xr = in + (size_t)row * DD;
    ushort2 u = ((const ushort2*)xr)[t];
    float vx = bf2f(u.x), vy = bf2f(u.y);
    float s = vx + vy, ss = vx * vx + vy * vy;
    float rs = wave_reduce_sum(s), rss = wave_reduce_sum(ss);
    int lane = t & 63, w = t >> 6;
    if (lane == 0) { red[w] = rs; red[8 + w] = rss; }
    __syncthreads();
    float mean = 0.f, msq = 0.f;
    #pragma unroll
    for (int i = 0; i < 4; ++i) { mean += red[i]; msq += red[8 + i]; }
    mean *= (1.0f / DD); msq *= (1.0f / DD);
    float rstd = rsqrtf(msq - mean * mean + 1e-5f);
    float2 gg = ((const float2*)g)[t], bb = ((const float2*)bta)[t];
    float2 o;
    o.x = (vx - mean) * rstd * gg.x + bb.x;
    o.y = (vy - mean) * rstd * gg.y + bb.y;
    ((float2*)(out + (size_t)row * DD))[t] = o;
}

// ---------------- LayerNorm (bf16 in, bf16 out) ----------------
__global__ __launch_bounds__(256) void ln_bf16_kernel(
    const unsigned short* __restrict__ in, unsigned short* __restrict__ out,
    const float* __restrict__ g, const float* __restrict__ bta)
{
    int row = blockIdx.x; int t = threadIdx.x;
    __shared__ float red[16];
    const unsigned short* xr = in + (size_t)row * DD;
    ushort2 u = ((const ushort2*)xr)[t];
    float vx = bf2f(u.x), vy = bf2f(u.y);
    float s = vx + vy, ss = vx * vx + vy * vy;
    float rs = wave_reduce_sum(s), rss = wave_reduce_sum(ss);
    int lane = t & 63, w = t >> 6;
    if (lane == 0) { red[w] = rs; red[8 + w] = rss; }
    __syncthreads();
    float mean = 0.f, msq = 0.f;
    #pragma unroll
    for (int i = 0; i < 4; ++i) { mean += red[i]; msq += red[8 + i]; }
    mean *= (1.0f / DD); msq *= (1.0f / DD);
    float rstd = rsqrtf(msq - mean * mean + 1e-5f);
    float2 gg = ((const float2*)g)[t], bb = ((const float2*)bta)[t];
    ushort2 o;
    o.x = f2bf((vx - mean) * rstd * gg.x + bb.x);
    o.y = f2bf((vy - mean) * rstd * gg.y + bb.y);
    ((ushort2*)(out + (size_t)row * DD))[t] = o;
}

extern "C" void kernel_launch(void* const* d_in, const int* in_sizes, int n_in,
                              void* d_out, int out_size, void* d_ws, size_t ws_size,
                              hipStream_t stream)
{
    const float* x          = (const float*)d_in[0];
    const int*   lengths    = (const int*)  d_in[1];
    const float* input_delay= (const float*)d_in[2];
    const float* c_local    = (const float*)d_in[3];
    const float* c_sink     = (const float*)d_in[4];
    const float* in_w       = (const float*)d_in[5];
    const float* in_b       = (const float*)d_in[6];
    const float* de_w1      = (const float*)d_in[7];
    const float* de_b1      = (const float*)d_in[8];
    const float* de_w2      = (const float*)d_in[9];
    const float* de_b2      = (const float*)d_in[10];
    const float* de_ln_g    = (const float*)d_in[11];
    const float* de_ln_b    = (const float*)d_in[12];
    const float* cpe_w      = (const float*)d_in[13];
    const float* cpe_b      = (const float*)d_in[14];
    const float* cpe_ln_g   = (const float*)d_in[15];
    const float* cpe_ln_b   = (const float*)d_in[16];
    const float* gain       = (const float*)d_in[17];
    const float* alpha      = (const float*)d_in[18];
    const float* beta       = (const float*)d_in[19];
    const float* floorp     = (const float*)d_in[20];
    const float* gammap     = (const float*)d_in[21];
    const float* inproj_w   = (const float*)d_in[22];
    const float* inproj_b   = (const float*)d_in[23];
    const float* outproj_w  = (const float*)d_in[24];
    const float* outproj_b  = (const float*)d_in[25];
    const float* ln1_g      = (const float*)d_in[26];
    const float* ln1_b      = (const float*)d_in[27];
    const float* ln2_g      = (const float*)d_in[28];
    const float* ln2_b      = (const float*)d_in[29];
    const float* ff_w1      = (const float*)d_in[30];
    const float* ff_b1      = (const float*)d_in[31];
    const float* ff_w2      = (const float*)d_in[32];
    const float* ff_b2      = (const float*)d_in[33];
    const float* out_ln_g   = (const float*)d_in[34];
    const float* out_ln_b   = (const float*)d_in[35];

    char* base = (char*)d_ws;
    unsigned short* h    = (unsigned short*)base;                     // 4 MB (bf16 residual)
    unsigned short* act1 = (unsigned short*)(base + 8u*1024*1024);    // 4 MB
    char* bigb          = base + 12u*1024*1024;                       // 16 MB shared region
    unsigned short* qkb  = (unsigned short*)bigb;                     // 8 MB (attn phase: Q,K)
    unsigned short* vtb  = (unsigned short*)(bigb + 12u*1024*1024);   // 4 MB (attn phase: V^T [512][4096])
    unsigned short* ffb  = (unsigned short*)bigb;                     // 16 MB (FF phase)
    unsigned short* Zb   = (unsigned short*)bigb;                     // 4.7 MB (embed phase)
    unsigned short* x_bf = (unsigned short*)(bigb + 5u*1024*1024);    // 0.5 MB
    float* cpe_pre       = (float*)(bigb + 8u*1024*1024);             // 8 MB
    unsigned short* w_inproj  = (unsigned short*)(base + 28u*1024*1024);
    unsigned short* w_outproj = w_inproj  + (size_t)3*1536*512;
    unsigned short* w_ff1     = w_outproj + (size_t)3*512*512;
    unsigned short* w_ff2     = w_ff1     + (size_t)3*2048*512;
    unsigned short* w_in      = w_ff2     + (size_t)3*512*2048;
    unsigned short* w_cpe     = w_in      + (size_t)512*64;
    float* e_pre              = (float*)(w_cpe + (size_t)512*FEATP);
    float* srow               = e_pre + (size_t)BB*DD;

    // small prologue: PE/z (1024) | small converts (256) | delay matvec (64)
    prologue_kernel<<<LL + 256 + 64, 256, 0, stream>>>(
        c_local, c_sink, lengths, beta, floorp, gammap, Zb, srow,
        x, in_w, cpe_w, x_bf, w_in, w_cpe,
        input_delay, de_w1, de_b1, de_w2, de_b2, e_pre);

    // h0 GEMM (bf16) + cpe GEMM + big-weight converts fused into one dispatch
    gemm_pre_dual<<<2048, 256, 0, stream>>>(x_bf, w_in, in_b, h, Zb, w_cpe, cpe_b, cpe_pre,
                                            inproj_w, outproj_w, ff_w1, ff_w2,
                                            w_inproj, w_outproj, w_ff1, w_ff2);
    embed_ep_kernel<<<MM, 256, 0, stream>>>(cpe_pre, e_pre, lengths, cpe_ln_g, cpe_ln_b,
                                            de_ln_g, de_ln_b, gain, h);

    for (int i = 0; i < NLAYER; ++i) {
        const unsigned short* wqk = w_inproj + (size_t)i * 1536 * 512;          // Q,K rows [0,1024)
        const unsigned short* wv  = wqk + (size_t)1024 * 512;                   // V rows [1024,1536)
        ln_bf16_kernel<<<MM, 256, 0, stream>>>(h, act1, ln1_g + (size_t)i * DD, ln1_b + (size_t)i * DD);
        gemm_qkv_dual<<<1536, 256, 0, stream>>>(act1, wqk, inproj_b + (size_t)i * 1536,
                                                qkb, wv, inproj_b + (size_t)i * 1536 + 1024, vtb);
        attn_mfma<<<512, 256, 0, stream>>>(qkb, vtb, c_local, srow, lengths, alpha, act1);
        gemm_t<64, 64, 2, 2, 2, 2><<<dim3(DD / 64, MM / 64), 256, 0, stream>>>(
            act1, w_outproj + (size_t)i * 512 * 512, outproj_b + (size_t)i * DD,
            h, nullptr, h, MM, DD, DD);
        ln_bf16_kernel<<<MM, 256, 0, stream>>>(h, act1, ln2_g + (size_t)i * DD, ln2_b + (size_t)i * DD);
        gemm_t<128, 128, 4, 4, 2, 3><<<dim3(DFF / 128, MM / 128), 256, 0, stream>>>(
            act1, w_ff1 + (size_t)i * 2048 * 512, ff_b1 + (size_t)i * DFF,
            nullptr, nullptr, ffb, MM, DFF, DD);
        gemm_t<64, 64, 2, 2, 2, 2><<<dim3(DD / 64, MM / 64), 256, 0, stream>>>(
            ffb, w_ff2 + (size_t)i * 512 * 2048, ff_b2 + (size_t)i * DD,
            h, nullptr, h, MM, DD, DFF);
    }
    ln_kernel<<<MM, 256, 0, stream>>>(h, (float*)d_out, out_ln_g, out_ln_b);
}